// Round 1
// baseline (734.005 us; speedup 1.0000x reference)
//
#include <hip/hip_runtime.h>
#include <hip/hip_bf16.h>
#include <stdint.h>

typedef unsigned short u16;

#define B_ 8
#define S_ 2048
#define Q_ 2048
#define D_ 1024
#define T_ 2048

typedef __attribute__((ext_vector_type(8))) short short8;
typedef __attribute__((ext_vector_type(4))) float f32x4;

__device__ __forceinline__ u16 f2b(float f) {
  union { float f; uint32_t u; } x; x.f = f;
  uint32_t r = x.u + 0x7fffu + ((x.u >> 16) & 1u);
  return (u16)(r >> 16);
}
__device__ __forceinline__ float b2f(u16 h) {
  union { uint32_t u; float f; } x; x.u = ((uint32_t)h) << 16;
  return x.f;
}
__device__ __forceinline__ float tanh_fast(float x) {
  // tanh(x) = 1 - 2/(exp(2x)+1); saturates correctly at +/-inf
  return 1.0f - 2.0f / (__expf(2.0f * x) + 1.0f);
}
__device__ __forceinline__ void async16(const void* g, void* l) {
  __builtin_amdgcn_global_load_lds(
      (const __attribute__((address_space(1))) void*)g,
      (__attribute__((address_space(3))) void*)l, 16, 0, 0);
}

// ---------------- elementwise cast f32 -> bf16 (4 elems/thread) ----------------
__global__ void cast_f32_bf16_k(const float* __restrict__ in, u16* __restrict__ out, int n4) {
  int i = blockIdx.x * 256 + threadIdx.x;
  if (i >= n4) return;
  float4 v = ((const float4*)in)[i];
  uint32_t lo = (uint32_t)f2b(v.x) | ((uint32_t)f2b(v.y) << 16);
  uint32_t hi = (uint32_t)f2b(v.z) | ((uint32_t)f2b(v.w) << 16);
  ((uint2*)out)[i] = make_uint2(lo, hi);
}

// ---------------- tiled transpose f32 (z,R,C) -> bf16 (z,C,R) ----------------
__global__ void transpose_f32_bf16_k(const float* __restrict__ in, u16* __restrict__ out,
                                     int R, int C) {
  __shared__ float tile[32][33];
  int z = blockIdx.z;
  const float* pin = in + (size_t)z * R * C;
  u16* pout = out + (size_t)z * R * C;
  int c0 = blockIdx.x * 32, r0 = blockIdx.y * 32;
  int tx = threadIdx.x, ty = threadIdx.y;  // blockDim (32,8)
#pragma unroll
  for (int k = 0; k < 32; k += 8)
    tile[ty + k][tx] = pin[(size_t)(r0 + ty + k) * C + (c0 + tx)];
  __syncthreads();
#pragma unroll
  for (int k = 0; k < 32; k += 8)
    pout[(size_t)(c0 + ty + k) * R + (r0 + tx)] = f2b(tile[tx][ty + k]);
}

// ---------------- tiled transpose bf16 (z,R,C) -> bf16 (z,C,R) ----------------
__global__ void transpose_bf16_k(const u16* __restrict__ in, u16* __restrict__ out,
                                 int R, int C) {
  __shared__ u16 tile[32][33];
  int z = blockIdx.z;
  const u16* pin = in + (size_t)z * R * C;
  u16* pout = out + (size_t)z * R * C;
  int c0 = blockIdx.x * 32, r0 = blockIdx.y * 32;
  int tx = threadIdx.x, ty = threadIdx.y;  // blockDim (32,8)
#pragma unroll
  for (int k = 0; k < 32; k += 8)
    tile[ty + k][tx] = pin[(size_t)(r0 + ty + k) * C + (c0 + tx)];
  __syncthreads();
#pragma unroll
  for (int k = 0; k < 32; k += 8)
    pout[(size_t)(c0 + ty + k) * R + (r0 + tx)] = tile[tx][ty + k];
}

// ---------------- row softmax: 1 block per row of length T (=2048) ----------------
__global__ void softmax_rows_k(const u16* __restrict__ in, u16* __restrict__ out, int T) {
  int row = blockIdx.x, tid = threadIdx.x;
  size_t base = (size_t)row * T + (size_t)tid * 8;
  uint4 raw = *(const uint4*)(in + base);
  uint32_t w[4] = {raw.x, raw.y, raw.z, raw.w};
  float f[8];
#pragma unroll
  for (int i = 0; i < 4; ++i) {
    f[2 * i]     = b2f((u16)(w[i] & 0xffffu));
    f[2 * i + 1] = b2f((u16)(w[i] >> 16));
  }
  float m = f[0];
#pragma unroll
  for (int i = 1; i < 8; ++i) m = fmaxf(m, f[i]);
  for (int s = 32; s > 0; s >>= 1) m = fmaxf(m, __shfl_xor(m, s));
  __shared__ float red[8];
  int wave = tid >> 6, lane = tid & 63;
  if (lane == 0) red[wave] = m;
  __syncthreads();
  m = fmaxf(fmaxf(red[0], red[1]), fmaxf(red[2], red[3]));
  float e[8], s = 0.0f;
#pragma unroll
  for (int i = 0; i < 8; ++i) { e[i] = __expf(f[i] - m); s += e[i]; }
  for (int k = 32; k > 0; k >>= 1) s += __shfl_xor(s, k);
  if (lane == 0) red[4 + wave] = s;
  __syncthreads();
  s = red[4] + red[5] + red[6] + red[7];
  float inv = 1.0f / s;
  uint32_t o[4];
#pragma unroll
  for (int i = 0; i < 4; ++i) {
    u16 a = f2b(e[2 * i] * inv);
    u16 b = f2b(e[2 * i + 1] * inv);
    o[i] = (uint32_t)a | ((uint32_t)b << 16);
  }
  *(uint4*)(out + base) = make_uint4(o[0], o[1], o[2], o[3]);
}

// ---------------- BT-GEMM: C[m,n] = sum_t sum_k A_t[m,k] * Bt_t[n,k] ----------------
// A row-major MxK (k-contiguous); B stored transposed NxK (k-contiguous).
// m batched: b = m0/Srows, s0 = m0%Srows. Epilogue mode: 0 tanh->bf16, 1 ->bf16, 2 ->f32.
__global__ __launch_bounds__(256) void gemm_bt_k(
    const u16* __restrict__ A1, long lda1, long bsA1,
    const u16* __restrict__ B1, long ldb1, long bsB1,
    const u16* __restrict__ A2, long lda2, long bsA2,
    const u16* __restrict__ B2, long ldb2, long bsB2,
    void* __restrict__ Cv, long ldc, long bsC,
    int K, int Srows, int nTerms, int mode) {
  __shared__ __align__(16) u16 lds_a[128 * 32];
  __shared__ __align__(16) u16 lds_b[128 * 32];
  const int m0 = blockIdx.y * 128;
  const int n0 = blockIdx.x * 128;
  const int b = m0 / Srows;
  const int s0 = m0 - b * Srows;
  const int tid = threadIdx.x;
  const int wave = tid >> 6, lane = tid & 63;
  const int wm = (wave >> 1) * 64, wn = (wave & 1) * 64;
  const int quad = lane >> 4, lrow = lane & 15;
  const int arow = lane >> 2, acol = (lane & 3) * 8;

  f32x4 acc[4][4];
  const f32x4 vzero = {0.0f, 0.0f, 0.0f, 0.0f};
#pragma unroll
  for (int i = 0; i < 4; ++i)
#pragma unroll
    for (int j = 0; j < 4; ++j) acc[i][j] = vzero;

  const u16* pA[2];
  const u16* pB[2];
  long la[2], lb[2];
  pA[0] = A1 + (size_t)bsA1 * b + (size_t)s0 * lda1;
  pB[0] = B1 + (size_t)bsB1 * b + (size_t)n0 * ldb1;
  pA[1] = (nTerms > 1) ? (A2 + (size_t)bsA2 * b + (size_t)s0 * lda2) : pA[0];
  pB[1] = (nTerms > 1) ? (B2 + (size_t)bsB2 * b + (size_t)n0 * ldb2) : pB[0];
  la[0] = lda1; la[1] = lda2;
  lb[0] = ldb1; lb[1] = ldb2;

  for (int t = 0; t < nTerms; ++t) {
    const u16* gA = pA[t];
    const u16* gB = pB[t];
    const long sA = la[t], sB = lb[t];
    for (int kt = 0; kt < K; kt += 32) {
      // stage 128x32 A-tile and 128x32 B^T-tile; rows packed, k-contiguous.
      // wave-uniform LDS base + lane*16B matches (row = lane/4, k = (lane%4)*8).
#pragma unroll
      for (int j = 0; j < 2; ++j) {
        const int rg = (j * 4 + wave) * 16;
        async16(gA + (size_t)(rg + arow) * sA + (kt + acol), &lds_a[rg * 32]);
        async16(gB + (size_t)(rg + arow) * sB + (kt + acol), &lds_b[rg * 32]);
      }
      __syncthreads();
      short8 af[4], bfr[4];
#pragma unroll
      for (int mi = 0; mi < 4; ++mi)
        af[mi] = *(const short8*)&lds_a[(wm + mi * 16 + lrow) * 32 + quad * 8];
#pragma unroll
      for (int ni = 0; ni < 4; ++ni)
        bfr[ni] = *(const short8*)&lds_b[(wn + ni * 16 + lrow) * 32 + quad * 8];
#pragma unroll
      for (int mi = 0; mi < 4; ++mi)
#pragma unroll
        for (int ni = 0; ni < 4; ++ni)
          acc[mi][ni] = __builtin_amdgcn_mfma_f32_16x16x32_bf16(af[mi], bfr[ni], acc[mi][ni], 0, 0, 0);
      __syncthreads();
    }
  }

  const size_t cbase = (size_t)bsC * b + (size_t)s0 * ldc + n0;
  if (mode == 2) {
    float* C = (float*)Cv + cbase;
#pragma unroll
    for (int mi = 0; mi < 4; ++mi)
#pragma unroll
      for (int ni = 0; ni < 4; ++ni) {
        const int rb = wm + mi * 16 + quad * 4;
        const int cc = wn + ni * 16 + lrow;
#pragma unroll
        for (int r = 0; r < 4; ++r)
          C[(size_t)(rb + r) * ldc + cc] = acc[mi][ni][r];
      }
  } else {
    u16* C = (u16*)Cv + cbase;
#pragma unroll
    for (int mi = 0; mi < 4; ++mi)
#pragma unroll
      for (int ni = 0; ni < 4; ++ni) {
        const int rb = wm + mi * 16 + quad * 4;
        const int cc = wn + ni * 16 + lrow;
#pragma unroll
        for (int r = 0; r < 4; ++r) {
          float v = acc[mi][ni][r];
          if (mode == 0) v = tanh_fast(v);
          C[(size_t)(rb + r) * ldc + cc] = f2b(v);
        }
      }
  }
}

extern "C" void kernel_launch(void* const* d_in, const int* in_sizes, int n_in,
                              void* d_out, int out_size, void* d_ws, size_t ws_size,
                              hipStream_t stream) {
  const float* src = (const float*)d_in[0];  // (B,S,D)
  const float* qry = (const float*)d_in[1];  // (B,Q,D)
  const float* ker = (const float*)d_in[2];  // (Q,T)  ("kernel")
  const float* wk  = (const float*)d_in[3];  // (D,Q)
  const float* wq  = (const float*)d_in[4];  // (S,D)
  float* out = (float*)d_out;                // (B,T,D)
  u16* ws = (u16*)d_ws;

  // workspace layout (halfwords); total ~252 MB
  u16* srcb  = ws;                                // (B,S,D) bf16
  u16* qryb  = srcb  + (size_t)B_ * S_ * D_;      // (B,Q,D) bf16
  u16* wqb   = qryb  + (size_t)B_ * Q_ * D_;      // (S,D) bf16
  u16* wkT   = wqb   + (size_t)S_ * D_;           // (Q,D) bf16
  u16* kerT  = wkT   + (size_t)D_ * Q_;           // (T,Q) bf16
  u16* srcT  = kerT  + (size_t)Q_ * T_;           // (B,D,S) bf16
  u16* tanhT = srcT  + (size_t)B_ * D_ * S_;      // (B,S,Q) bf16; later reused for sm
  u16* simb  = tanhT + (size_t)B_ * S_ * Q_;      // (B,S,T) bf16; later reused for sm^T

  dim3 tb(32, 8);

  // casts (layout-preserving)
  cast_f32_bf16_k<<<(B_ * S_ * D_) / 1024, 256, 0, stream>>>(src, srcb, (B_ * S_ * D_) / 4);
  cast_f32_bf16_k<<<(B_ * Q_ * D_) / 1024, 256, 0, stream>>>(qry, qryb, (B_ * Q_ * D_) / 4);
  cast_f32_bf16_k<<<(S_ * D_) / 1024, 256, 0, stream>>>(wq, wqb, (S_ * D_) / 4);

  // transposes to N x K layouts
  transpose_f32_bf16_k<<<dim3(Q_ / 32, D_ / 32, 1), tb, 0, stream>>>(wk, wkT, D_, Q_);
  transpose_f32_bf16_k<<<dim3(T_ / 32, Q_ / 32, 1), tb, 0, stream>>>(ker, kerT, Q_, T_);
  transpose_f32_bf16_k<<<dim3(D_ / 32, S_ / 32, B_), tb, 0, stream>>>(src, srcT, S_, D_);

  // GEMM1: tanh(src@wk^T' + wq@query^T') -> tanhT  (M=B*S, N=Q, K=D, 2 terms)
  gemm_bt_k<<<dim3(Q_ / 128, (B_ * S_) / 128), 256, 0, stream>>>(
      srcb, D_, (long)S_ * D_,
      wkT, D_, 0,
      wqb, D_, 0,
      qryb, D_, (long)Q_ * D_,
      tanhT, Q_, (long)S_ * Q_,
      D_, S_, 2, 0);

  // GEMM2: sim = tanhT @ kernel -> simb  (M=B*S, N=T, K=Q)
  gemm_bt_k<<<dim3(T_ / 128, (B_ * S_) / 128), 256, 0, stream>>>(
      tanhT, Q_, (long)S_ * Q_,
      kerT, Q_, 0,
      nullptr, 0, 0, nullptr, 0, 0,
      simb, T_, (long)S_ * T_,
      Q_, S_, 1, 1);

  // softmax rows of simb -> sm (reuse tanhT)
  softmax_rows_k<<<B_ * S_, 256, 0, stream>>>(simb, tanhT, T_);

  // sm (B,S,T) -> sm^T (B,T,S) (reuse simb)
  transpose_bf16_k<<<dim3(T_ / 32, S_ / 32, B_), tb, 0, stream>>>(tanhT, simb, S_, T_);

  // GEMM3: out[b] = sm^T[b] @ src[b]  (M=B*T, N=D, K=S), fp32 epilogue
  gemm_bt_k<<<dim3(D_ / 128, (B_ * T_) / 128), 256, 0, stream>>>(
      simb, S_, (long)T_ * S_,
      srcT, S_, (long)D_ * S_,
      nullptr, 0, 0, nullptr, 0, 0,
      out, D_, (long)T_ * D_,
      S_, T_, 1, 2);
}

// Round 2
// 696.196 us; speedup vs baseline: 1.0543x; 1.0543x over previous
//
#include <hip/hip_runtime.h>
#include <hip/hip_bf16.h>
#include <stdint.h>

typedef unsigned short u16;

#define B_ 8
#define S_ 2048
#define Q_ 2048
#define D_ 1024
#define T_ 2048

// LDS tile: 128 rows x 64 cols bf16, stored as 16 groups of 8 rows (1 KB)
// with 32 B pad between groups -> group stride 264 words == 8 mod 32 banks.
#define GRP 528  // u16 stride per 8-row group (1024 B data + 32 B pad)

typedef __attribute__((ext_vector_type(8))) short short8;
typedef __attribute__((ext_vector_type(16))) float f32x16;

__device__ __forceinline__ u16 f2b(float f) {
  union { float f; uint32_t u; } x; x.f = f;
  uint32_t r = x.u + 0x7fffu + ((x.u >> 16) & 1u);
  return (u16)(r >> 16);
}
__device__ __forceinline__ float b2f(u16 h) {
  union { uint32_t u; float f; } x; x.u = ((uint32_t)h) << 16;
  return x.f;
}
__device__ __forceinline__ float tanh_fast(float x) {
  return 1.0f - 2.0f / (__expf(2.0f * x) + 1.0f);
}
__device__ __forceinline__ void async16(const void* g, void* l) {
  __builtin_amdgcn_global_load_lds(
      (const __attribute__((address_space(1))) void*)g,
      (__attribute__((address_space(3))) void*)l, 16, 0, 0);
}

// ---------------- elementwise cast f32 -> bf16 (4 elems/thread) ----------------
__global__ void cast_f32_bf16_k(const float* __restrict__ in, u16* __restrict__ out, int n4) {
  int i = blockIdx.x * 256 + threadIdx.x;
  if (i >= n4) return;
  float4 v = ((const float4*)in)[i];
  uint32_t lo = (uint32_t)f2b(v.x) | ((uint32_t)f2b(v.y) << 16);
  uint32_t hi = (uint32_t)f2b(v.z) | ((uint32_t)f2b(v.w) << 16);
  ((uint2*)out)[i] = make_uint2(lo, hi);
}

// ---------------- tiled transpose f32 (z,R,C) -> bf16 (z,C,R) ----------------
__global__ void transpose_f32_bf16_k(const float* __restrict__ in, u16* __restrict__ out,
                                     int R, int C) {
  __shared__ float tile[32][33];
  int z = blockIdx.z;
  const float* pin = in + (size_t)z * R * C;
  u16* pout = out + (size_t)z * R * C;
  int c0 = blockIdx.x * 32, r0 = blockIdx.y * 32;
  int tx = threadIdx.x, ty = threadIdx.y;  // blockDim (32,8)
#pragma unroll
  for (int k = 0; k < 32; k += 8)
    tile[ty + k][tx] = pin[(size_t)(r0 + ty + k) * C + (c0 + tx)];
  __syncthreads();
#pragma unroll
  for (int k = 0; k < 32; k += 8)
    pout[(size_t)(c0 + ty + k) * R + (r0 + tx)] = f2b(tile[tx][ty + k]);
}

// ------------- src prep: f32 (b,S,D) -> bf16 copy (b,S,D) + bf16 transpose (b,D,S) -------------
__global__ void src_prep_k(const float* __restrict__ in, u16* __restrict__ outc,
                           u16* __restrict__ outT) {
  __shared__ float tile[32][33];
  int z = blockIdx.z;
  const float* pin = in + (size_t)z * S_ * D_;
  u16* pc = outc + (size_t)z * S_ * D_;
  u16* pt = outT + (size_t)z * S_ * D_;
  int c0 = blockIdx.x * 32, r0 = blockIdx.y * 32;  // r over S, c over D
  int tx = threadIdx.x, ty = threadIdx.y;
#pragma unroll
  for (int k = 0; k < 32; k += 8) {
    float v = pin[(size_t)(r0 + ty + k) * D_ + (c0 + tx)];
    tile[ty + k][tx] = v;
    pc[(size_t)(r0 + ty + k) * D_ + (c0 + tx)] = f2b(v);
  }
  __syncthreads();
#pragma unroll
  for (int k = 0; k < 32; k += 8)
    pt[(size_t)(c0 + ty + k) * S_ + (r0 + tx)] = f2b(tile[tx][ty + k]);
}

// ---------------- row stats: max + 1/sum(exp) per row of length T ----------------
__global__ void rowstat_k(const u16* __restrict__ in, float2* __restrict__ ml, int T) {
  int row = blockIdx.x, tid = threadIdx.x;
  size_t base = (size_t)row * T + (size_t)tid * 8;
  uint4 raw = *(const uint4*)(in + base);
  uint32_t w[4] = {raw.x, raw.y, raw.z, raw.w};
  float f[8];
#pragma unroll
  for (int i = 0; i < 4; ++i) {
    f[2 * i]     = b2f((u16)(w[i] & 0xffffu));
    f[2 * i + 1] = b2f((u16)(w[i] >> 16));
  }
  float m = f[0];
#pragma unroll
  for (int i = 1; i < 8; ++i) m = fmaxf(m, f[i]);
  for (int s = 32; s > 0; s >>= 1) m = fmaxf(m, __shfl_xor(m, s));
  __shared__ float red[8];
  int wave = tid >> 6, lane = tid & 63;
  if (lane == 0) red[wave] = m;
  __syncthreads();
  m = fmaxf(fmaxf(red[0], red[1]), fmaxf(red[2], red[3]));
  float s = 0.0f;
#pragma unroll
  for (int i = 0; i < 8; ++i) s += __expf(f[i] - m);
  for (int k = 32; k > 0; k >>= 1) s += __shfl_xor(s, k);
  if (lane == 0) red[4 + wave] = s;
  __syncthreads();
  if (tid == 0) {
    s = red[4] + red[5] + red[6] + red[7];
    ml[row] = make_float2(m, 1.0f / s);
  }
}

// ------- fused normalize + transpose: sim (b,S,T) + ml -> smT (b,T,S) bf16 -------
__global__ void sm_transpose_k(const u16* __restrict__ sim, const float2* __restrict__ ml,
                               u16* __restrict__ smT) {
  __shared__ u16 tile[32][33];
  int z = blockIdx.z;
  const u16* pin = sim + (size_t)z * S_ * T_;
  u16* pout = smT + (size_t)z * T_ * S_;
  int c0 = blockIdx.x * 32, r0 = blockIdx.y * 32;  // r over S (softmax rows), c over T
  int tx = threadIdx.x, ty = threadIdx.y;
#pragma unroll
  for (int k = 0; k < 32; k += 8)
    tile[ty + k][tx] = pin[(size_t)(r0 + ty + k) * T_ + (c0 + tx)];
  float2 p = ml[(size_t)z * S_ + r0 + tx];  // stats for softmax-row (r0+tx)
  __syncthreads();
#pragma unroll
  for (int k = 0; k < 32; k += 8)
    pout[(size_t)(c0 + ty + k) * S_ + (r0 + tx)] =
        f2b(__expf(b2f(tile[tx][ty + k]) - p.x) * p.y);
}

// ---------------- BT-GEMM: C[m,n] = sum_t sum_k A_t[m,k] * Bt_t[n,k] ----------------
// 128x128 block tile, BK=64, 32x32x16 bf16 MFMA, 2x2 waves each with 2x2 MFMA tiles.
// A row-major MxK (k-contig); B stored transposed NxK (k-contig). K % 64 == 0.
// mode: 0 tanh->bf16, 1 ->bf16, 2 ->f32.
__global__ __launch_bounds__(256) void gemm_bt_k(
    const u16* __restrict__ A1, long lda1, long bsA1,
    const u16* __restrict__ B1, long ldb1, long bsB1,
    const u16* __restrict__ A2, long lda2, long bsA2,
    const u16* __restrict__ B2, long ldb2, long bsB2,
    void* __restrict__ Cv, long ldc, long bsC,
    int K, int Srows, int nTerms, int mode) {
  __shared__ __align__(16) u16 lds_a[16 * GRP];
  __shared__ __align__(16) u16 lds_b[16 * GRP];
  const int m0 = blockIdx.y * 128;
  const int n0 = blockIdx.x * 128;
  const int b = m0 / Srows;
  const int s0 = m0 - b * Srows;
  const int tid = threadIdx.x;
  const int wave = tid >> 6, lane = tid & 63;
  const int wm = (wave >> 1) * 64, wn = (wave & 1) * 64;
  const int l31 = lane & 31, hi = lane >> 5;
  const int srow = lane >> 3, scol = (lane & 7) * 8;  // staging: 8 rows x 64 cols per inst

  // frag u16 offsets into padded tile: addr(r,c) = (r>>3)*GRP + (r&7)*64 + c
  const int rA0 = wm + l31,      rA1 = wm + 32 + l31;
  const int rB0 = wn + l31,      rB1 = wn + 32 + l31;
  const int offA0 = (rA0 >> 3) * GRP + (rA0 & 7) * 64 + hi * 8;
  const int offA1 = (rA1 >> 3) * GRP + (rA1 & 7) * 64 + hi * 8;
  const int offB0 = (rB0 >> 3) * GRP + (rB0 & 7) * 64 + hi * 8;
  const int offB1 = (rB1 >> 3) * GRP + (rB1 & 7) * 64 + hi * 8;

  f32x16 acc[2][2];
#pragma unroll
  for (int i = 0; i < 2; ++i)
#pragma unroll
    for (int j = 0; j < 2; ++j)
#pragma unroll
      for (int r = 0; r < 16; ++r) acc[i][j][r] = 0.0f;

  const u16* pA[2];
  const u16* pB[2];
  long la[2], lb[2];
  pA[0] = A1 + (size_t)bsA1 * b + (size_t)s0 * lda1;
  pB[0] = B1 + (size_t)bsB1 * b + (size_t)n0 * ldb1;
  pA[1] = (nTerms > 1) ? (A2 + (size_t)bsA2 * b + (size_t)s0 * lda2) : pA[0];
  pB[1] = (nTerms > 1) ? (B2 + (size_t)bsB2 * b + (size_t)n0 * ldb2) : pB[0];
  la[0] = lda1; la[1] = lda2;
  lb[0] = ldb1; lb[1] = ldb2;

  for (int t = 0; t < nTerms; ++t) {
    const u16* gA = pA[t];
    const u16* gB = pB[t];
    const long sA = la[t], sB = lb[t];
    for (int kt = 0; kt < K; kt += 64) {
      // stage 128x64 A and B^T tiles; each wave DMAs 4 groups of 8 rows per tile.
#pragma unroll
      for (int j = 0; j < 4; ++j) {
        const int ga = j * 4 + wave;
        async16(gA + (size_t)(ga * 8 + srow) * sA + (kt + scol), &lds_a[ga * GRP]);
        async16(gB + (size_t)(ga * 8 + srow) * sB + (kt + scol), &lds_b[ga * GRP]);
      }
      __syncthreads();
#pragma unroll
      for (int kk = 0; kk < 4; ++kk) {
        short8 a0 = *(const short8*)&lds_a[offA0 + kk * 16];
        short8 a1 = *(const short8*)&lds_a[offA1 + kk * 16];
        short8 b0 = *(const short8*)&lds_b[offB0 + kk * 16];
        short8 b1 = *(const short8*)&lds_b[offB1 + kk * 16];
        acc[0][0] = __builtin_amdgcn_mfma_f32_32x32x16_bf16(a0, b0, acc[0][0], 0, 0, 0);
        acc[0][1] = __builtin_amdgcn_mfma_f32_32x32x16_bf16(a0, b1, acc[0][1], 0, 0, 0);
        acc[1][0] = __builtin_amdgcn_mfma_f32_32x32x16_bf16(a1, b0, acc[1][0], 0, 0, 0);
        acc[1][1] = __builtin_amdgcn_mfma_f32_32x32x16_bf16(a1, b1, acc[1][1], 0, 0, 0);
      }
      __syncthreads();
    }
  }

  // C/D layout (32x32): col = lane&31, row = (reg&3) + 8*(reg>>2) + 4*(lane>>5)
  const size_t cbase = (size_t)bsC * b + (size_t)s0 * ldc + n0;
  if (mode == 2) {
    float* C = (float*)Cv + cbase;
#pragma unroll
    for (int mi = 0; mi < 2; ++mi)
#pragma unroll
      for (int ni = 0; ni < 2; ++ni) {
        const int col = wn + ni * 32 + l31;
#pragma unroll
        for (int r = 0; r < 16; ++r) {
          const int row = wm + mi * 32 + (r & 3) + 8 * (r >> 2) + 4 * hi;
          C[(size_t)row * ldc + col] = acc[mi][ni][r];
        }
      }
  } else {
    u16* C = (u16*)Cv + cbase;
#pragma unroll
    for (int mi = 0; mi < 2; ++mi)
#pragma unroll
      for (int ni = 0; ni < 2; ++ni) {
        const int col = wn + ni * 32 + l31;
#pragma unroll
        for (int r = 0; r < 16; ++r) {
          const int row = wm + mi * 32 + (r & 3) + 8 * (r >> 2) + 4 * hi;
          float v = acc[mi][ni][r];
          if (mode == 0) v = tanh_fast(v);
          C[(size_t)row * ldc + col] = f2b(v);
        }
      }
  }
}

extern "C" void kernel_launch(void* const* d_in, const int* in_sizes, int n_in,
                              void* d_out, int out_size, void* d_ws, size_t ws_size,
                              hipStream_t stream) {
  const float* src = (const float*)d_in[0];  // (B,S,D)
  const float* qry = (const float*)d_in[1];  // (B,Q,D)
  const float* ker = (const float*)d_in[2];  // (Q,T)
  const float* wk  = (const float*)d_in[3];  // (D,Q)
  const float* wq  = (const float*)d_in[4];  // (S,D)
  float* out = (float*)d_out;                // (B,T,D)
  u16* ws = (u16*)d_ws;

  // workspace layout (halfwords); total ~252 MB
  u16* srcb  = ws;                                // (B,S,D) bf16
  u16* qryb  = srcb  + (size_t)B_ * S_ * D_;      // (B,Q,D) bf16
  u16* wqb   = qryb  + (size_t)B_ * Q_ * D_;      // (S,D) bf16
  u16* wkT   = wqb   + (size_t)S_ * D_;           // (Q,D) bf16; reused for ml after GEMM2
  u16* kerT  = wkT   + (size_t)D_ * Q_;           // (T,Q) bf16
  u16* srcT  = kerT  + (size_t)Q_ * T_;           // (B,D,S) bf16
  u16* tanhT = srcT  + (size_t)B_ * D_ * S_;      // (B,S,Q) bf16; reused for smT
  u16* simb  = tanhT + (size_t)B_ * S_ * Q_;      // (B,S,T) bf16
  float2* ml = (float2*)wkT;                      // (B*S) {max, 1/sum}, 128 KB

  dim3 tb(32, 8);

  // prep: casts + transposes
  cast_f32_bf16_k<<<(B_ * Q_ * D_) / 1024, 256, 0, stream>>>(qry, qryb, (B_ * Q_ * D_) / 4);
  cast_f32_bf16_k<<<(S_ * D_) / 1024, 256, 0, stream>>>(wq, wqb, (S_ * D_) / 4);
  transpose_f32_bf16_k<<<dim3(Q_ / 32, D_ / 32, 1), tb, 0, stream>>>(wk, wkT, D_, Q_);
  transpose_f32_bf16_k<<<dim3(T_ / 32, Q_ / 32, 1), tb, 0, stream>>>(ker, kerT, Q_, T_);
  src_prep_k<<<dim3(D_ / 32, S_ / 32, B_), tb, 0, stream>>>(src, srcb, srcT);

  // GEMM1: tanh(src@wk + wq@q_t) -> tanhT  (M=B*S, N=Q, K=D, 2 terms)
  gemm_bt_k<<<dim3(Q_ / 128, (B_ * S_) / 128), 256, 0, stream>>>(
      srcb, D_, (long)S_ * D_,
      wkT, D_, 0,
      wqb, D_, 0,
      qryb, D_, (long)Q_ * D_,
      tanhT, Q_, (long)S_ * Q_,
      D_, S_, 2, 0);

  // GEMM2: sim = tanhT @ kernel -> simb  (M=B*S, N=T, K=Q)
  gemm_bt_k<<<dim3(T_ / 128, (B_ * S_) / 128), 256, 0, stream>>>(
      tanhT, Q_, (long)S_ * Q_,
      kerT, Q_, 0,
      nullptr, 0, 0, nullptr, 0, 0,
      simb, T_, (long)S_ * T_,
      Q_, S_, 1, 1);

  // softmax stats per row of simb (note: wkT/ml aliasing is safe — kerT used above, wkT done)
  rowstat_k<<<B_ * S_, 256, 0, stream>>>(simb, ml, T_);

  // fused normalize + transpose: sim -> smT (B,T,S) (reuse tanhT)
  sm_transpose_k<<<dim3(T_ / 32, S_ / 32, B_), tb, 0, stream>>>(simb, ml, tanhT);

  // GEMM3: out[b] = smT[b] @ src[b]  (M=B*T, N=D, K=S), fp32 epilogue
  gemm_bt_k<<<dim3(D_ / 128, (B_ * T_) / 128), 256, 0, stream>>>(
      tanhT, S_, (long)T_ * S_,
      srcT, S_, (long)D_ * S_,
      nullptr, 0, 0, nullptr, 0, 0,
      out, D_, (long)T_ * D_,
      S_, T_, 1, 2);
}

// Round 3
// 647.047 us; speedup vs baseline: 1.1344x; 1.0760x over previous
//
#include <hip/hip_runtime.h>
#include <hip/hip_bf16.h>
#include <stdint.h>

typedef unsigned short u16;

#define B_ 8
#define S_ 2048
#define Q_ 2048
#define D_ 1024
#define T_ 2048

// LDS tile: 128 rows x 64 cols bf16, stored as 16 groups of 8 rows (1 KB)
// with 32 B pad between groups -> group stride 264 words == 8 mod 32 banks.
#define GRP 528  // u16 stride per 8-row group (1024 B data + 32 B pad)

typedef __attribute__((ext_vector_type(8))) short short8;
typedef __attribute__((ext_vector_type(16))) float f32x16;

__device__ __forceinline__ u16 f2b(float f) {
  union { float f; uint32_t u; } x; x.f = f;
  uint32_t r = x.u + 0x7fffu + ((x.u >> 16) & 1u);
  return (u16)(r >> 16);
}
__device__ __forceinline__ float b2f(u16 h) {
  union { uint32_t u; float f; } x; x.u = ((uint32_t)h) << 16;
  return x.f;
}
__device__ __forceinline__ float tanh_fast(float x) {
  return 1.0f - 2.0f / (__expf(2.0f * x) + 1.0f);
}
__device__ __forceinline__ void async16(const void* g, void* l) {
  __builtin_amdgcn_global_load_lds(
      (const __attribute__((address_space(1))) void*)g,
      (__attribute__((address_space(3))) void*)l, 16, 0, 0);
}

// ---------------- elementwise cast f32 -> bf16 (4 elems/thread) ----------------
__global__ void cast_f32_bf16_k(const float* __restrict__ in, u16* __restrict__ out, int n4) {
  int i = blockIdx.x * 256 + threadIdx.x;
  if (i >= n4) return;
  float4 v = ((const float4*)in)[i];
  uint32_t lo = (uint32_t)f2b(v.x) | ((uint32_t)f2b(v.y) << 16);
  uint32_t hi = (uint32_t)f2b(v.z) | ((uint32_t)f2b(v.w) << 16);
  ((uint2*)out)[i] = make_uint2(lo, hi);
}

// ---------------- tiled transpose f32 (z,R,C) -> bf16 (z,C,R) ----------------
__global__ void transpose_f32_bf16_k(const float* __restrict__ in, u16* __restrict__ out,
                                     int R, int C) {
  __shared__ float tile[32][33];
  int z = blockIdx.z;
  const float* pin = in + (size_t)z * R * C;
  u16* pout = out + (size_t)z * R * C;
  int c0 = blockIdx.x * 32, r0 = blockIdx.y * 32;
  int tx = threadIdx.x, ty = threadIdx.y;  // blockDim (32,8)
#pragma unroll
  for (int k = 0; k < 32; k += 8)
    tile[ty + k][tx] = pin[(size_t)(r0 + ty + k) * C + (c0 + tx)];
  __syncthreads();
#pragma unroll
  for (int k = 0; k < 32; k += 8)
    pout[(size_t)(c0 + ty + k) * R + (r0 + tx)] = f2b(tile[tx][ty + k]);
}

// ------------- src prep: f32 (b,S,D) -> bf16 copy (b,S,D) + bf16 transpose (b,D,S) -------------
__global__ void src_prep_k(const float* __restrict__ in, u16* __restrict__ outc,
                           u16* __restrict__ outT) {
  __shared__ float tile[32][33];
  int z = blockIdx.z;
  const float* pin = in + (size_t)z * S_ * D_;
  u16* pc = outc + (size_t)z * S_ * D_;
  u16* pt = outT + (size_t)z * S_ * D_;
  int c0 = blockIdx.x * 32, r0 = blockIdx.y * 32;  // r over S, c over D
  int tx = threadIdx.x, ty = threadIdx.y;
#pragma unroll
  for (int k = 0; k < 32; k += 8) {
    float v = pin[(size_t)(r0 + ty + k) * D_ + (c0 + tx)];
    tile[ty + k][tx] = v;
    pc[(size_t)(r0 + ty + k) * D_ + (c0 + tx)] = f2b(v);
  }
  __syncthreads();
#pragma unroll
  for (int k = 0; k < 32; k += 8)
    pt[(size_t)(c0 + ty + k) * S_ + (r0 + tx)] = f2b(tile[tx][ty + k]);
}

// ---------------- row stats: max + 1/sum(exp) per row of length T ----------------
__global__ void rowstat_k(const u16* __restrict__ in, float2* __restrict__ ml, int T) {
  int row = blockIdx.x, tid = threadIdx.x;
  size_t base = (size_t)row * T + (size_t)tid * 8;
  uint4 raw = *(const uint4*)(in + base);
  uint32_t w[4] = {raw.x, raw.y, raw.z, raw.w};
  float f[8];
#pragma unroll
  for (int i = 0; i < 4; ++i) {
    f[2 * i]     = b2f((u16)(w[i] & 0xffffu));
    f[2 * i + 1] = b2f((u16)(w[i] >> 16));
  }
  float m = f[0];
#pragma unroll
  for (int i = 1; i < 8; ++i) m = fmaxf(m, f[i]);
  for (int s = 32; s > 0; s >>= 1) m = fmaxf(m, __shfl_xor(m, s));
  __shared__ float red[8];
  int wave = tid >> 6, lane = tid & 63;
  if (lane == 0) red[wave] = m;
  __syncthreads();
  m = fmaxf(fmaxf(red[0], red[1]), fmaxf(red[2], red[3]));
  float s = 0.0f;
#pragma unroll
  for (int i = 0; i < 8; ++i) s += __expf(f[i] - m);
  for (int k = 32; k > 0; k >>= 1) s += __shfl_xor(s, k);
  if (lane == 0) red[4 + wave] = s;
  __syncthreads();
  if (tid == 0) {
    s = red[4] + red[5] + red[6] + red[7];
    ml[row] = make_float2(m, 1.0f / s);
  }
}

// ------- fused normalize + transpose: sim (b,S,T) + ml -> smT (b,T,S) bf16 -------
__global__ void sm_transpose_k(const u16* __restrict__ sim, const float2* __restrict__ ml,
                               u16* __restrict__ smT) {
  __shared__ u16 tile[32][33];
  int z = blockIdx.z;
  const u16* pin = sim + (size_t)z * S_ * T_;
  u16* pout = smT + (size_t)z * T_ * S_;
  int c0 = blockIdx.x * 32, r0 = blockIdx.y * 32;  // r over S (softmax rows), c over T
  int tx = threadIdx.x, ty = threadIdx.y;
#pragma unroll
  for (int k = 0; k < 32; k += 8)
    tile[ty + k][tx] = pin[(size_t)(r0 + ty + k) * T_ + (c0 + tx)];
  float2 p = ml[(size_t)z * S_ + r0 + tx];  // stats for softmax-row (r0+tx)
  __syncthreads();
#pragma unroll
  for (int k = 0; k < 32; k += 8)
    pout[(size_t)(c0 + ty + k) * S_ + (r0 + tx)] =
        f2b(__expf(b2f(tile[tx][ty + k]) - p.x) * p.y);
}

// ---------------- BT-GEMM: C[m,n] = sum_t sum_k A_t[m,k] * Bt_t[n,k] ----------------
// 128x128 block tile, BK=64, 32x32x16 bf16 MFMA, 2x2 waves each with 2x2 MFMA tiles.
// A row-major MxK (k-contig); B stored transposed NxK (k-contig). K % 64 == 0.
// mode: 0 tanh->bf16, 1 ->bf16, 2 ->f32.
// __launch_bounds__(256, 4): cap 128 regs/wave so 4 blocks/CU co-reside
// (LDS 33 KB x 4 = 132 KB <= 160 KB). Cross-block overlap hides the
// vmcnt(0)+barrier drain that pinned MfmaUtil at 32% with ~2 blocks/CU.
__global__ __launch_bounds__(256, 4) void gemm_bt_k(
    const u16* __restrict__ A1, long lda1, long bsA1,
    const u16* __restrict__ B1, long ldb1, long bsB1,
    const u16* __restrict__ A2, long lda2, long bsA2,
    const u16* __restrict__ B2, long ldb2, long bsB2,
    void* __restrict__ Cv, long ldc, long bsC,
    int K, int Srows, int nTerms, int mode) {
  __shared__ __align__(16) u16 lds_a[16 * GRP];
  __shared__ __align__(16) u16 lds_b[16 * GRP];
  const int m0 = blockIdx.y * 128;
  const int n0 = blockIdx.x * 128;
  const int b = m0 / Srows;
  const int s0 = m0 - b * Srows;
  const int tid = threadIdx.x;
  const int wave = tid >> 6, lane = tid & 63;
  const int wm = (wave >> 1) * 64, wn = (wave & 1) * 64;
  const int l31 = lane & 31, hi = lane >> 5;
  const int srow = lane >> 3, scol = (lane & 7) * 8;  // staging: 8 rows x 64 cols per inst

  // frag u16 offsets into padded tile: addr(r,c) = (r>>3)*GRP + (r&7)*64 + c
  const int rA0 = wm + l31,      rA1 = wm + 32 + l31;
  const int rB0 = wn + l31,      rB1 = wn + 32 + l31;
  const int offA0 = (rA0 >> 3) * GRP + (rA0 & 7) * 64 + hi * 8;
  const int offA1 = (rA1 >> 3) * GRP + (rA1 & 7) * 64 + hi * 8;
  const int offB0 = (rB0 >> 3) * GRP + (rB0 & 7) * 64 + hi * 8;
  const int offB1 = (rB1 >> 3) * GRP + (rB1 & 7) * 64 + hi * 8;

  f32x16 acc[2][2];
#pragma unroll
  for (int i = 0; i < 2; ++i)
#pragma unroll
    for (int j = 0; j < 2; ++j)
#pragma unroll
      for (int r = 0; r < 16; ++r) acc[i][j][r] = 0.0f;

  const u16* pA[2];
  const u16* pB[2];
  long la[2], lb[2];
  pA[0] = A1 + (size_t)bsA1 * b + (size_t)s0 * lda1;
  pB[0] = B1 + (size_t)bsB1 * b + (size_t)n0 * ldb1;
  pA[1] = (nTerms > 1) ? (A2 + (size_t)bsA2 * b + (size_t)s0 * lda2) : pA[0];
  pB[1] = (nTerms > 1) ? (B2 + (size_t)bsB2 * b + (size_t)n0 * ldb2) : pB[0];
  la[0] = lda1; la[1] = lda2;
  lb[0] = ldb1; lb[1] = ldb2;

  for (int t = 0; t < nTerms; ++t) {
    const u16* gA = pA[t];
    const u16* gB = pB[t];
    const long sA = la[t], sB = lb[t];
    for (int kt = 0; kt < K; kt += 64) {
      // stage 128x64 A and B^T tiles; each wave DMAs 4 groups of 8 rows per tile.
#pragma unroll
      for (int j = 0; j < 4; ++j) {
        const int ga = j * 4 + wave;
        async16(gA + (size_t)(ga * 8 + srow) * sA + (kt + scol), &lds_a[ga * GRP]);
        async16(gB + (size_t)(ga * 8 + srow) * sB + (kt + scol), &lds_b[ga * GRP]);
      }
      __syncthreads();
#pragma unroll
      for (int kk = 0; kk < 4; ++kk) {
        short8 a0 = *(const short8*)&lds_a[offA0 + kk * 16];
        short8 a1 = *(const short8*)&lds_a[offA1 + kk * 16];
        short8 b0 = *(const short8*)&lds_b[offB0 + kk * 16];
        short8 b1 = *(const short8*)&lds_b[offB1 + kk * 16];
        acc[0][0] = __builtin_amdgcn_mfma_f32_32x32x16_bf16(a0, b0, acc[0][0], 0, 0, 0);
        acc[0][1] = __builtin_amdgcn_mfma_f32_32x32x16_bf16(a0, b1, acc[0][1], 0, 0, 0);
        acc[1][0] = __builtin_amdgcn_mfma_f32_32x32x16_bf16(a1, b0, acc[1][0], 0, 0, 0);
        acc[1][1] = __builtin_amdgcn_mfma_f32_32x32x16_bf16(a1, b1, acc[1][1], 0, 0, 0);
      }
      __syncthreads();
    }
  }

  // C/D layout (32x32): col = lane&31, row = (reg&3) + 8*(reg>>2) + 4*(lane>>5)
  const size_t cbase = (size_t)bsC * b + (size_t)s0 * ldc + n0;
  if (mode == 2) {
    float* C = (float*)Cv + cbase;
#pragma unroll
    for (int mi = 0; mi < 2; ++mi)
#pragma unroll
      for (int ni = 0; ni < 2; ++ni) {
        const int col = wn + ni * 32 + l31;
#pragma unroll
        for (int r = 0; r < 16; ++r) {
          const int row = wm + mi * 32 + (r & 3) + 8 * (r >> 2) + 4 * hi;
          C[(size_t)row * ldc + col] = acc[mi][ni][r];
        }
      }
  } else {
    u16* C = (u16*)Cv + cbase;
#pragma unroll
    for (int mi = 0; mi < 2; ++mi)
#pragma unroll
      for (int ni = 0; ni < 2; ++ni) {
        const int col = wn + ni * 32 + l31;
#pragma unroll
        for (int r = 0; r < 16; ++r) {
          const int row = wm + mi * 32 + (r & 3) + 8 * (r >> 2) + 4 * hi;
          float v = acc[mi][ni][r];
          if (mode == 0) v = tanh_fast(v);
          C[(size_t)row * ldc + col] = f2b(v);
        }
      }
  }
}

extern "C" void kernel_launch(void* const* d_in, const int* in_sizes, int n_in,
                              void* d_out, int out_size, void* d_ws, size_t ws_size,
                              hipStream_t stream) {
  const float* src = (const float*)d_in[0];  // (B,S,D)
  const float* qry = (const float*)d_in[1];  // (B,Q,D)
  const float* ker = (const float*)d_in[2];  // (Q,T)
  const float* wk  = (const float*)d_in[3];  // (D,Q)
  const float* wq  = (const float*)d_in[4];  // (S,D)
  float* out = (float*)d_out;                // (B,T,D)
  u16* ws = (u16*)d_ws;

  // workspace layout (halfwords); total ~252 MB
  u16* srcb  = ws;                                // (B,S,D) bf16
  u16* qryb  = srcb  + (size_t)B_ * S_ * D_;      // (B,Q,D) bf16
  u16* wqb   = qryb  + (size_t)B_ * Q_ * D_;      // (S,D) bf16
  u16* wkT   = wqb   + (size_t)S_ * D_;           // (Q,D) bf16; reused for ml after GEMM2
  u16* kerT  = wkT   + (size_t)D_ * Q_;           // (T,Q) bf16
  u16* srcT  = kerT  + (size_t)Q_ * T_;           // (B,D,S) bf16
  u16* tanhT = srcT  + (size_t)B_ * D_ * S_;      // (B,S,Q) bf16; reused for smT
  u16* simb  = tanhT + (size_t)B_ * S_ * Q_;      // (B,S,T) bf16
  float2* ml = (float2*)wkT;                      // (B*S) {max, 1/sum}, 128 KB

  dim3 tb(32, 8);

  // prep: casts + transposes
  cast_f32_bf16_k<<<(B_ * Q_ * D_) / 1024, 256, 0, stream>>>(qry, qryb, (B_ * Q_ * D_) / 4);
  cast_f32_bf16_k<<<(S_ * D_) / 1024, 256, 0, stream>>>(wq, wqb, (S_ * D_) / 4);
  transpose_f32_bf16_k<<<dim3(Q_ / 32, D_ / 32, 1), tb, 0, stream>>>(wk, wkT, D_, Q_);
  transpose_f32_bf16_k<<<dim3(T_ / 32, Q_ / 32, 1), tb, 0, stream>>>(ker, kerT, Q_, T_);
  src_prep_k<<<dim3(D_ / 32, S_ / 32, B_), tb, 0, stream>>>(src, srcb, srcT);

  // GEMM1: tanh(src@wk + wq@q_t) -> tanhT  (M=B*S, N=Q, K=D, 2 terms)
  gemm_bt_k<<<dim3(Q_ / 128, (B_ * S_) / 128), 256, 0, stream>>>(
      srcb, D_, (long)S_ * D_,
      wkT, D_, 0,
      wqb, D_, 0,
      qryb, D_, (long)Q_ * D_,
      tanhT, Q_, (long)S_ * Q_,
      D_, S_, 2, 0);

  // GEMM2: sim = tanhT @ kernel -> simb  (M=B*S, N=T, K=Q)
  gemm_bt_k<<<dim3(T_ / 128, (B_ * S_) / 128), 256, 0, stream>>>(
      tanhT, Q_, (long)S_ * Q_,
      kerT, Q_, 0,
      nullptr, 0, 0, nullptr, 0, 0,
      simb, T_, (long)S_ * T_,
      Q_, S_, 1, 1);

  // softmax stats per row of simb (wkT/ml aliasing safe — wkT consumed in GEMM1)
  rowstat_k<<<B_ * S_, 256, 0, stream>>>(simb, ml, T_);

  // fused normalize + transpose: sim -> smT (B,T,S) (reuse tanhT)
  sm_transpose_k<<<dim3(T_ / 32, S_ / 32, B_), tb, 0, stream>>>(simb, ml, tanhT);

  // GEMM3: out[b] = smT[b] @ src[b]  (M=B*T, N=D, K=S), fp32 epilogue
  gemm_bt_k<<<dim3(D_ / 128, (B_ * T_) / 128), 256, 0, stream>>>(
      tanhT, S_, (long)T_ * S_,
      srcT, S_, (long)D_ * S_,
      nullptr, 0, 0, nullptr, 0, 0,
      out, D_, (long)T_ * D_,
      S_, T_, 1, 2);
}

// Round 4
// 632.800 us; speedup vs baseline: 1.1599x; 1.0225x over previous
//
#include <hip/hip_runtime.h>
#include <hip/hip_bf16.h>
#include <stdint.h>

typedef unsigned short u16;

#define B_ 8
#define S_ 2048
#define Q_ 2048
#define D_ 1024
#define T_ 2048

// GEMM LDS tile: 128 rows x 64 cols bf16, 16 groups of 8 rows (1 KB)
// with 32 B pad between groups -> group stride 264 B == 8 banks mod 32.
#define GRP 528  // u16 stride per 8-row group

typedef __attribute__((ext_vector_type(8))) short short8;
typedef __attribute__((ext_vector_type(16))) float f32x16;

__device__ __forceinline__ u16 f2b(float f) {
  union { float f; uint32_t u; } x; x.f = f;
  uint32_t r = x.u + 0x7fffu + ((x.u >> 16) & 1u);
  return (u16)(r >> 16);
}
__device__ __forceinline__ float b2f(u16 h) {
  union { uint32_t u; float f; } x; x.u = ((uint32_t)h) << 16;
  return x.f;
}
__device__ __forceinline__ float tanh_fast(float x) {
  return 1.0f - 2.0f / (__expf(2.0f * x) + 1.0f);
}
__device__ __forceinline__ void async16(const void* g, void* l) {
  __builtin_amdgcn_global_load_lds(
      (const __attribute__((address_space(1))) void*)g,
      (__attribute__((address_space(3))) void*)l, 16, 0, 0);
}

// ---------------- elementwise cast f32 -> bf16 (4 elems/thread) ----------------
__global__ void cast_f32_bf16_k(const float* __restrict__ in, u16* __restrict__ out, int n4) {
  int i = blockIdx.x * 256 + threadIdx.x;
  if (i >= n4) return;
  float4 v = ((const float4*)in)[i];
  uint32_t lo = (uint32_t)f2b(v.x) | ((uint32_t)f2b(v.y) << 16);
  uint32_t hi = (uint32_t)f2b(v.z) | ((uint32_t)f2b(v.w) << 16);
  ((uint2*)out)[i] = make_uint2(lo, hi);
}

// ------- tiled transpose f32 (z,R,C) -> bf16 (z,C,R); 64x64 tile, vector IO -------
__global__ void transpose_f32_bf16_v(const float* __restrict__ in, u16* __restrict__ out,
                                     int R, int C) {
  __shared__ u16 t[64 * 72];
  int z = blockIdx.z;
  const float* pin = in + (size_t)z * R * C;
  u16* pout = out + (size_t)z * R * C;
  int c0 = blockIdx.x * 64, r0 = blockIdx.y * 64;
  int tid = threadIdx.x;
  int rr = tid >> 4, c4 = (tid & 15) * 4;
#pragma unroll
  for (int p = 0; p < 4; ++p) {
    int r = p * 16 + rr;
    float4 v = *(const float4*)&pin[(size_t)(r0 + r) * C + c0 + c4];
    t[(c4 + 0) * 72 + r] = f2b(v.x);
    t[(c4 + 1) * 72 + r] = f2b(v.y);
    t[(c4 + 2) * 72 + r] = f2b(v.z);
    t[(c4 + 3) * 72 + r] = f2b(v.w);
  }
  __syncthreads();
  int ct = tid >> 3, r8 = (tid & 7) * 8;
#pragma unroll
  for (int p = 0; p < 2; ++p) {
    int c = p * 32 + ct;
    uint2 lo = *(const uint2*)&t[c * 72 + r8];
    uint2 hi = *(const uint2*)&t[c * 72 + r8 + 4];
    *(uint4*)&pout[(size_t)(c0 + c) * R + r0 + r8] = make_uint4(lo.x, lo.y, hi.x, hi.y);
  }
}

// --- src prep: f32 (b,S,D) -> bf16 copy (b,S,D) + bf16 transpose (b,D,S); vector IO ---
__global__ void src_prep_v(const float* __restrict__ in, u16* __restrict__ outc,
                           u16* __restrict__ outT) {
  __shared__ u16 t[64 * 72];
  int z = blockIdx.z;
  const float* pin = in + (size_t)z * S_ * D_;
  u16* pc = outc + (size_t)z * S_ * D_;
  u16* pt = outT + (size_t)z * S_ * D_;
  int c0 = blockIdx.x * 64, r0 = blockIdx.y * 64;  // r over S, c over D
  int tid = threadIdx.x;
  int rr = tid >> 4, c4 = (tid & 15) * 4;
#pragma unroll
  for (int p = 0; p < 4; ++p) {
    int r = p * 16 + rr;
    float4 v = *(const float4*)&pin[(size_t)(r0 + r) * D_ + c0 + c4];
    u16 b0 = f2b(v.x), b1 = f2b(v.y), b2 = f2b(v.z), b3 = f2b(v.w);
    uint2 pk;
    pk.x = (uint32_t)b0 | ((uint32_t)b1 << 16);
    pk.y = (uint32_t)b2 | ((uint32_t)b3 << 16);
    *(uint2*)&pc[(size_t)(r0 + r) * D_ + c0 + c4] = pk;
    t[(c4 + 0) * 72 + r] = b0;
    t[(c4 + 1) * 72 + r] = b1;
    t[(c4 + 2) * 72 + r] = b2;
    t[(c4 + 3) * 72 + r] = b3;
  }
  __syncthreads();
  int ct = tid >> 3, r8 = (tid & 7) * 8;
#pragma unroll
  for (int p = 0; p < 2; ++p) {
    int c = p * 32 + ct;
    uint2 lo = *(const uint2*)&t[c * 72 + r8];
    uint2 hi = *(const uint2*)&t[c * 72 + r8 + 4];
    *(uint4*)&pt[(size_t)(c0 + c) * S_ + r0 + r8] = make_uint4(lo.x, lo.y, hi.x, hi.y);
  }
}

// ------- scale srcT (b,d,s) in place by 1/l[b*S+s]; 8 elems/thread -------
__global__ void scale_srcT_k(u16* __restrict__ srcT, const float* __restrict__ l) {
  size_t i = (size_t)blockIdx.x * 256 + threadIdx.x;  // group of 8 u16
  size_t e0 = i * 8;
  int s8 = (int)(e0 & (S_ - 1));
  int bb = (int)(e0 / ((size_t)D_ * S_));
  const float* lp = l + (size_t)bb * S_ + s8;
  float4 l0 = *(const float4*)lp;
  float4 l1 = *(const float4*)(lp + 4);
  uint4 raw = *(uint4*)&srcT[e0];
  uint32_t w[4] = {raw.x, raw.y, raw.z, raw.w};
  float li[8] = {l0.x, l0.y, l0.z, l0.w, l1.x, l1.y, l1.z, l1.w};
  uint32_t o[4];
#pragma unroll
  for (int k = 0; k < 4; ++k) {
    float a = b2f((u16)(w[k] & 0xffffu)) / li[2 * k];
    float b = b2f((u16)(w[k] >> 16)) / li[2 * k + 1];
    o[k] = (uint32_t)f2b(a) | ((uint32_t)f2b(b) << 16);
  }
  *(uint4*)&srcT[e0] = make_uint4(o[0], o[1], o[2], o[3]);
}

// ---------------- BT-GEMM: C[m,n] = sum_t sum_k A_t[m,k] * Bt_t[n,k] ----------------
// 128x128 tile, BK=64, 32x32x16 bf16 MFMA, 2x2 waves x 2x2 MFMA tiles.
// mode: 0 tanh->bf16, 1 ->bf16, 2 ->f32,
//       3 P=exp(C) -> transposed bf16 write (Cv is (b,N,M), ldc=M-stride) + row-sum
//         atomicAdd into lsum[b*Srows + m] (max-free softmax; |sim| bounded ~39).
// __launch_bounds__(256,4): 128 regs/wave -> 4 blocks/CU (LDS 33 KB x 4 = 132 <= 160 KB).
__global__ __launch_bounds__(256, 4) void gemm_bt_k(
    const u16* __restrict__ A1, long lda1, long bsA1,
    const u16* __restrict__ B1, long ldb1, long bsB1,
    const u16* __restrict__ A2, long lda2, long bsA2,
    const u16* __restrict__ B2, long ldb2, long bsB2,
    void* __restrict__ Cv, long ldc, long bsC,
    int K, int Srows, int nTerms, int mode, float* __restrict__ lsum) {
  __shared__ __align__(16) u16 lds_all[32 * GRP];  // 33792 B; a-tile then b-tile
  u16* lds_a = lds_all;
  u16* lds_b = lds_all + 16 * GRP;
  const int m0 = blockIdx.y * 128;
  const int n0 = blockIdx.x * 128;
  const int b = m0 / Srows;
  const int s0 = m0 - b * Srows;
  const int tid = threadIdx.x;
  const int wave = tid >> 6, lane = tid & 63;
  const int wm = (wave >> 1) * 64, wn = (wave & 1) * 64;
  const int l31 = lane & 31, hi = lane >> 5;
  const int srow = lane >> 3, scol = (lane & 7) * 8;

  const int rA0 = wm + l31,      rA1 = wm + 32 + l31;
  const int rB0 = wn + l31,      rB1 = wn + 32 + l31;
  const int offA0 = (rA0 >> 3) * GRP + (rA0 & 7) * 64 + hi * 8;
  const int offA1 = (rA1 >> 3) * GRP + (rA1 & 7) * 64 + hi * 8;
  const int offB0 = (rB0 >> 3) * GRP + (rB0 & 7) * 64 + hi * 8;
  const int offB1 = (rB1 >> 3) * GRP + (rB1 & 7) * 64 + hi * 8;

  f32x16 acc[2][2];
#pragma unroll
  for (int i = 0; i < 2; ++i)
#pragma unroll
    for (int j = 0; j < 2; ++j)
#pragma unroll
      for (int r = 0; r < 16; ++r) acc[i][j][r] = 0.0f;

  const u16* pA[2];
  const u16* pB[2];
  long la[2], lb[2];
  pA[0] = A1 + (size_t)bsA1 * b + (size_t)s0 * lda1;
  pB[0] = B1 + (size_t)bsB1 * b + (size_t)n0 * ldb1;
  pA[1] = (nTerms > 1) ? (A2 + (size_t)bsA2 * b + (size_t)s0 * lda2) : pA[0];
  pB[1] = (nTerms > 1) ? (B2 + (size_t)bsB2 * b + (size_t)n0 * ldb2) : pB[0];
  la[0] = lda1; la[1] = lda2;
  lb[0] = ldb1; lb[1] = ldb2;

  for (int t = 0; t < nTerms; ++t) {
    const u16* gA = pA[t];
    const u16* gB = pB[t];
    const long sA = la[t], sB = lb[t];
    for (int kt = 0; kt < K; kt += 64) {
#pragma unroll
      for (int j = 0; j < 4; ++j) {
        const int ga = j * 4 + wave;
        async16(gA + (size_t)(ga * 8 + srow) * sA + (kt + scol), &lds_a[ga * GRP]);
        async16(gB + (size_t)(ga * 8 + srow) * sB + (kt + scol), &lds_b[ga * GRP]);
      }
      __syncthreads();
#pragma unroll
      for (int kk = 0; kk < 4; ++kk) {
        short8 a0 = *(const short8*)&lds_a[offA0 + kk * 16];
        short8 a1 = *(const short8*)&lds_a[offA1 + kk * 16];
        short8 b0 = *(const short8*)&lds_b[offB0 + kk * 16];
        short8 b1 = *(const short8*)&lds_b[offB1 + kk * 16];
        acc[0][0] = __builtin_amdgcn_mfma_f32_32x32x16_bf16(a0, b0, acc[0][0], 0, 0, 0);
        acc[0][1] = __builtin_amdgcn_mfma_f32_32x32x16_bf16(a0, b1, acc[0][1], 0, 0, 0);
        acc[1][0] = __builtin_amdgcn_mfma_f32_32x32x16_bf16(a1, b0, acc[1][0], 0, 0, 0);
        acc[1][1] = __builtin_amdgcn_mfma_f32_32x32x16_bf16(a1, b1, acc[1][1], 0, 0, 0);
      }
      __syncthreads();
    }
  }

  // C/D layout (32x32): col = lane&31, row = (reg&3) + 8*(reg>>2) + 4*(lane>>5)
  if (mode == 3) {
    // 1) in-place exp
#pragma unroll
    for (int mi = 0; mi < 2; ++mi)
#pragma unroll
      for (int ni = 0; ni < 2; ++ni)
#pragma unroll
        for (int r = 0; r < 16; ++r)
          acc[mi][ni][r] = __expf(acc[mi][ni][r]);
    // 2) row sums over this block's 128 cols -> atomicAdd lsum
    float* lrow = lsum + (size_t)b * Srows + s0;
#pragma unroll
    for (int mi = 0; mi < 2; ++mi)
#pragma unroll
      for (int r = 0; r < 16; ++r) {
        float pv = acc[mi][0][r] + acc[mi][1][r];
        pv += __shfl_xor(pv, 1);
        pv += __shfl_xor(pv, 2);
        pv += __shfl_xor(pv, 4);
        pv += __shfl_xor(pv, 8);
        pv += __shfl_xor(pv, 16);
        const int row = wm + mi * 32 + (r & 3) + 8 * (r >> 2) + 4 * hi;
        if (l31 == 0) atomicAdd(&lrow[row], pv);
      }
    // 3) transpose via LDS tile [t][s], u16 stride 132 (128*132 = 16896 u16 = full LDS)
#pragma unroll
    for (int mi = 0; mi < 2; ++mi)
#pragma unroll
      for (int ni = 0; ni < 2; ++ni) {
        const int col = wn + ni * 32 + l31;  // t index
#pragma unroll
        for (int g = 0; g < 4; ++g) {
          const int rowb = wm + mi * 32 + g * 8 + 4 * hi;  // 4 consecutive s
          u16 p0 = f2b(acc[mi][ni][g * 4 + 0]);
          u16 p1 = f2b(acc[mi][ni][g * 4 + 1]);
          u16 p2 = f2b(acc[mi][ni][g * 4 + 2]);
          u16 p3 = f2b(acc[mi][ni][g * 4 + 3]);
          uint2 pk;
          pk.x = (uint32_t)p0 | ((uint32_t)p1 << 16);
          pk.y = (uint32_t)p2 | ((uint32_t)p3 << 16);
          *(uint2*)&lds_all[col * 132 + rowb] = pk;
        }
      }
    __syncthreads();
    // 4) coalesced transposed write: P^T[b, n0+t, s0+s]
    u16* gP = (u16*)Cv + (size_t)bsC * b + (size_t)n0 * ldc + s0;
    const int tl = tid >> 4, s8 = (tid & 15) * 8;
#pragma unroll
    for (int p = 0; p < 8; ++p) {
      const int tt = p * 16 + tl;
      uint2 lo = *(const uint2*)&lds_all[tt * 132 + s8];
      uint2 hi2 = *(const uint2*)&lds_all[tt * 132 + s8 + 4];
      *(uint4*)&gP[(size_t)tt * ldc + s8] = make_uint4(lo.x, lo.y, hi2.x, hi2.y);
    }
    return;
  }

  const size_t cbase = (size_t)bsC * b + (size_t)s0 * ldc + n0;
  if (mode == 2) {
    float* C = (float*)Cv + cbase;
#pragma unroll
    for (int mi = 0; mi < 2; ++mi)
#pragma unroll
      for (int ni = 0; ni < 2; ++ni) {
        const int col = wn + ni * 32 + l31;
#pragma unroll
        for (int r = 0; r < 16; ++r) {
          const int row = wm + mi * 32 + (r & 3) + 8 * (r >> 2) + 4 * hi;
          C[(size_t)row * ldc + col] = acc[mi][ni][r];
        }
      }
  } else {
    u16* C = (u16*)Cv + cbase;
#pragma unroll
    for (int mi = 0; mi < 2; ++mi)
#pragma unroll
      for (int ni = 0; ni < 2; ++ni) {
        const int col = wn + ni * 32 + l31;
#pragma unroll
        for (int r = 0; r < 16; ++r) {
          const int row = wm + mi * 32 + (r & 3) + 8 * (r >> 2) + 4 * hi;
          float v = acc[mi][ni][r];
          if (mode == 0) v = tanh_fast(v);
          C[(size_t)row * ldc + col] = f2b(v);
        }
      }
  }
}

extern "C" void kernel_launch(void* const* d_in, const int* in_sizes, int n_in,
                              void* d_out, int out_size, void* d_ws, size_t ws_size,
                              hipStream_t stream) {
  const float* src = (const float*)d_in[0];  // (B,S,D)
  const float* qry = (const float*)d_in[1];  // (B,Q,D)
  const float* ker = (const float*)d_in[2];  // (Q,T)
  const float* wk  = (const float*)d_in[3];  // (D,Q)
  const float* wq  = (const float*)d_in[4];  // (S,D)
  float* out = (float*)d_out;                // (B,T,D)
  u16* ws = (u16*)d_ws;

  // workspace layout (halfwords); ~240 MB
  u16* srcb  = ws;                                // (B,S,D) bf16
  u16* qryb  = srcb  + (size_t)B_ * S_ * D_;      // (B,Q,D) bf16
  u16* wqb   = qryb  + (size_t)B_ * Q_ * D_;      // (S,D) bf16
  u16* wkT   = wqb   + (size_t)S_ * D_;           // (Q,D) bf16
  u16* kerT  = wkT   + (size_t)D_ * Q_;           // (T,Q) bf16
  u16* srcT  = kerT  + (size_t)Q_ * T_;           // (B,D,S) bf16; scaled in place by 1/l
  u16* tanhT = srcT  + (size_t)B_ * D_ * S_;      // (B,S,Q) bf16
  u16* PT    = tanhT + (size_t)B_ * S_ * Q_;      // (B,T,S) bf16 = exp(sim)^T
  float* l   = (float*)(PT + (size_t)B_ * T_ * S_);  // (B*S) row sums

  dim3 tb(256);

  // prep
  cast_f32_bf16_k<<<(B_ * Q_ * D_) / 1024, 256, 0, stream>>>(qry, qryb, (B_ * Q_ * D_) / 4);
  cast_f32_bf16_k<<<(S_ * D_) / 1024, 256, 0, stream>>>(wq, wqb, (S_ * D_) / 4);
  transpose_f32_bf16_v<<<dim3(Q_ / 64, D_ / 64, 1), tb, 0, stream>>>(wk, wkT, D_, Q_);
  transpose_f32_bf16_v<<<dim3(T_ / 64, Q_ / 64, 1), tb, 0, stream>>>(ker, kerT, Q_, T_);
  src_prep_v<<<dim3(D_ / 64, S_ / 64, B_), tb, 0, stream>>>(src, srcb, srcT);
  hipMemsetAsync(l, 0, (size_t)B_ * S_ * sizeof(float), stream);

  // GEMM1: tanh(src@wk + wq@q_t) -> tanhT  (M=B*S, N=Q, K=D, 2 terms)
  gemm_bt_k<<<dim3(Q_ / 128, (B_ * S_) / 128), 256, 0, stream>>>(
      srcb, D_, (long)S_ * D_,
      wkT, D_, 0,
      wqb, D_, 0,
      qryb, D_, (long)Q_ * D_,
      tanhT, Q_, (long)S_ * Q_,
      D_, S_, 2, 0, nullptr);

  // GEMM2: P^T = exp(tanhT @ kernel)^T -> PT (B,T,S); row sums -> l  (M=B*S, N=T, K=Q)
  gemm_bt_k<<<dim3(T_ / 128, (B_ * S_) / 128), 256, 0, stream>>>(
      tanhT, Q_, (long)S_ * Q_,
      kerT, Q_, 0,
      nullptr, 0, 0, nullptr, 0, 0,
      PT, S_, (long)T_ * S_,
      Q_, S_, 1, 3, l);

  // scale srcT by 1/l (in place)
  scale_srcT_k<<<(B_ * D_ * S_) / (256 * 8), 256, 0, stream>>>(srcT, l);

  // GEMM3: out[b] = PT[b] @ srcT_scaled[b]  (M=B*T, N=D, K=S), fp32 epilogue
  gemm_bt_k<<<dim3(D_ / 128, (B_ * T_) / 128), 256, 0, stream>>>(
      PT, S_, (long)T_ * S_,
      srcT, S_, (long)D_ * S_,
      nullptr, 0, 0, nullptr, 0, 0,
      out, D_, (long)T_ * D_,
      S_, T_, 1, 2, nullptr);
}